// Round 1
// 880.316 us; speedup vs baseline: 1.1505x; 1.1505x over previous
//
#include <hip/hip_runtime.h>

// CovariantEvolutionBlock on MI355X (gfx950).
// I/O is float32 (bf16-grid values); internal compute bf16 MFMA + fp32 accum.
// B=2, L=2048, D=1024, H=16, HD=64, N=B*L=4096 tokens.

typedef unsigned short u16;
typedef __attribute__((ext_vector_type(8))) short short8;
typedef __attribute__((ext_vector_type(8))) unsigned short us8;
typedef __attribute__((ext_vector_type(4))) float f32x4;
typedef __attribute__((ext_vector_type(4))) unsigned short us4;

__device__ __forceinline__ float b2f(u16 u) {
    union { unsigned u; float f; } c; c.u = ((unsigned)u) << 16; return c.f;
}
__device__ __forceinline__ u16 f2b(float f) {
    union { float f; unsigned u; } c; c.f = f;
    unsigned x = c.u;
    unsigned r = (x + 0x7fffu + ((x >> 16) & 1u)) >> 16;   // RNE
    return (u16)r;
}
__device__ __forceinline__ float fast_rcp(float x) {
    return __builtin_amdgcn_rcpf(x);     // v_rcp_f32, ~1 ulp, fine pre-bf16
}

__device__ __forceinline__ void async_copy16(const u16* g, u16* l) {
    __builtin_amdgcn_global_load_lds(
        (const __attribute__((address_space(1))) unsigned int*)(g),
        (__attribute__((address_space(3))) unsigned int*)(l), 16, 0, 0);
}

// ---------------------------------------------------------------------------
// fp32 -> bf16 conversion, 4 elems/thread. n must be a multiple of 1024.
__global__ __launch_bounds__(256) void cvt_k(const float* __restrict__ s,
                                             u16* __restrict__ d, int n) {
    int i = (blockIdx.x * 256 + threadIdx.x) * 4;
    if (i >= n) return;
    f32x4 v = *(const f32x4*)(s + i);
    us4 o;
#pragma unroll
    for (int k = 0; k < 4; k++) o[k] = f2b(v[k]);
    *(us4*)(d + i) = o;
}

// ---------------------------------------------------------------------------
// RMSNorm from fp32 input: one block per token, D=1024, 256 threads x 4 contig.
__global__ __launch_bounds__(256) void rmsf_k(const float* __restrict__ x,
                                              const float* __restrict__ w,
                                              u16* __restrict__ y, int D) {
    int n = blockIdx.x;
    const float* xr = x + (size_t)n * D;
    int i0 = threadIdx.x << 2;
    f32x4 v = *(const f32x4*)(xr + i0);
    float s = v[0] * v[0] + v[1] * v[1] + v[2] * v[2] + v[3] * v[3];
#pragma unroll
    for (int m = 32; m >= 1; m >>= 1) s += __shfl_xor(s, m, 64);
    __shared__ float red[4];
    if ((threadIdx.x & 63) == 0) red[threadIdx.x >> 6] = s;
    __syncthreads();
    float tot = red[0] + red[1] + red[2] + red[3];
    float scale = rsqrtf(tot / (float)D + 1e-6f);
    f32x4 wv = *(const f32x4*)(w + i0);
    us4 o;
#pragma unroll
    for (int k = 0; k < 4; k++) o[k] = f2b(v[k] * scale * wv[k]);
    *(us4*)(y + (size_t)n * D + i0) = o;
}

// RMSNorm from bf16 (internal) input.
__global__ __launch_bounds__(256) void rmsb_k(const u16* __restrict__ x,
                                              const float* __restrict__ w,
                                              u16* __restrict__ y, int D) {
    int n = blockIdx.x;
    const u16* xr = x + (size_t)n * D;
    int i0 = threadIdx.x << 2;
    us4 xv = *(const us4*)(xr + i0);
    float v[4]; float s = 0.f;
#pragma unroll
    for (int k = 0; k < 4; k++) { v[k] = b2f(xv[k]); s += v[k] * v[k]; }
#pragma unroll
    for (int m = 32; m >= 1; m >>= 1) s += __shfl_xor(s, m, 64);
    __shared__ float red[4];
    if ((threadIdx.x & 63) == 0) red[threadIdx.x >> 6] = s;
    __syncthreads();
    float tot = red[0] + red[1] + red[2] + red[3];
    float scale = rsqrtf(tot / (float)D + 1e-6f);
    f32x4 wv = *(const f32x4*)(w + i0);
    us4 o;
#pragma unroll
    for (int k = 0; k < 4; k++) o[k] = f2b(v[k] * scale * wv[k]);
    *(us4*)(y + (size_t)n * D + i0) = o;
}

// ---------------------------------------------------------------------------
// Tiled NT GEMM: C[n,o] = act(sum_k A[n,k]*W[o,k] + bias[o]).
// BM=128 x BN(template 128|64) tile, BK=32, 4 waves (2x2), global_load_lds
// staging, LDS double-buffer (one barrier per K-iter), XOR-swizzled k-groups.
// BN=64 doubles block count for O=1024 outputs (1 -> 2 blocks/CU occupancy;
// the extra A-panel re-reads are L2-resident 512KB panels).
// act: 0=none 1=silu 2=tanh. grid = (O/BN, M/128).
// mode: 0 = row-major C[row*O+col]; 1 = per-head transpose for attention V:
//       C is VT[((b*16+h)*64 + d)*2048 + tok]  (B=2,H=16,HD=64,L=2048).
template <int BN>
__global__ __launch_bounds__(256) void gemm_t(const u16* __restrict__ A,
                                              const u16* __restrict__ W,
                                              const float* __restrict__ bias,
                                              u16* __restrict__ C,
                                              int K, int O, int act, int mode) {
    constexpr int NJ = BN / 32;          // n-subtiles per wave: 4 or 2
    constexpr int WN = BN / 2;           // wave n-extent: 64 or 32
    __shared__ u16 Asm[2][128 * 32];
    __shared__ u16 Bsm[2][BN * 32];

    const int tid = threadIdx.x;
    const int wid = tid >> 6, lane = tid & 63;
    const int l15 = lane & 15, quad = lane >> 4;
    const int row0 = blockIdx.y * 128, col0 = blockIdx.x * BN;
    const int wm = (wid >> 1) << 6, wn = (wid & 1) * WN;

    const int sr = tid >> 2;
    const int sc = tid & 3;
    const int ga = sc ^ ((sr ^ (sr >> 2)) & 3);
    const u16* aS0 = A + (size_t)(row0 + sr) * K + ga * 8;
    const u16* aS1 = A + (size_t)(row0 + 64 + sr) * K + ga * 8;
    const u16* bS0 = W + (size_t)(col0 + sr) * K + ga * 8;
    const u16* bS1 = W + (size_t)(col0 + 64 + sr) * K + ga * 8;  // BN=128 only

    const int qa = quad ^ ((l15 ^ (l15 >> 2)) & 3);

    f32x4 acc[4][NJ];
#pragma unroll
    for (int i = 0; i < 4; i++)
#pragma unroll
        for (int j = 0; j < NJ; j++) acc[i][j] = (f32x4){0.f, 0.f, 0.f, 0.f};

    const int wbs = wid << 9;
    auto stage = [&](int buf, int kof) {
        async_copy16(aS0 + kof, &Asm[buf][wbs]);
        async_copy16(aS1 + kof, &Asm[buf][2048 + wbs]);
        async_copy16(bS0 + kof, &Bsm[buf][wbs]);
        if constexpr (BN == 128) async_copy16(bS1 + kof, &Bsm[buf][2048 + wbs]);
    };

    const int nk = K >> 5;
    stage(0, 0);
    __syncthreads();
    for (int kk = 0; kk < nk; kk++) {
        int cur = kk & 1;
        if (kk + 1 < nk) stage(1 - cur, (kk + 1) << 5);
        const u16* Ab = Asm[cur];
        const u16* Bb = Bsm[cur];
        short8 af[4], bf[NJ];
#pragma unroll
        for (int i = 0; i < 4; i++)
            af[i] = *(const short8*)&Ab[(wm + i * 16 + l15) * 32 + qa * 8];
#pragma unroll
        for (int j = 0; j < NJ; j++)
            bf[j] = *(const short8*)&Bb[(wn + j * 16 + l15) * 32 + qa * 8];
#pragma unroll
        for (int i = 0; i < 4; i++)
#pragma unroll
            for (int j = 0; j < NJ; j++)
                acc[i][j] = __builtin_amdgcn_mfma_f32_16x16x32_bf16(af[i], bf[j], acc[i][j], 0, 0, 0);
        __syncthreads();
    }

    if (mode == 0) {
#pragma unroll
        for (int j = 0; j < NJ; j++) {
            int col = col0 + wn + j * 16 + l15;
            float bb = bias ? bias[col] : 0.f;
#pragma unroll
            for (int i = 0; i < 4; i++) {
                int rowb = row0 + wm + i * 16 + (quad << 2);
#pragma unroll
                for (int g = 0; g < 4; g++) {
                    float v = acc[i][j][g] + bb;
                    if (act == 1) {                      // silu
                        v = v * fast_rcp(1.f + __expf(-v));
                    } else if (act == 2) {               // tanh = 1 - 2/(e^2x+1)
                        float t = __expf(v * 2.f);
                        v = 1.f - 2.f * fast_rcp(1.f + t);
                    }
                    C[(size_t)(rowb + g) * O + col] = f2b(v);
                }
            }
        }
    } else {
        // V-transpose epilogue: 4 consecutive toks -> one 8B store VT[bh][d][tok].
#pragma unroll
        for (int j = 0; j < NJ; j++) {
            int col = col0 + wn + j * 16 + l15;     // h*64 + d
            int h = col >> 6, d = col & 63;
#pragma unroll
            for (int i = 0; i < 4; i++) {
                int rowb = row0 + wm + i * 16 + (quad << 2);
                int bb_ = rowb >> 11;               // batch
                int tok = rowb & 2047;
                us4 pk;
#pragma unroll
                for (int g = 0; g < 4; g++) pk[g] = f2b(acc[i][j][g]);
                *(us4*)&C[(size_t)(((bb_ << 4) + h) * 64 + d) * 2048 + tok] = pk;
            }
        }
    }
}

// ---------------------------------------------------------------------------
// Sigmoid attention v3: block-cooperative flash-style.
// Block = 256 thr = 4 waves = 128 queries of one (b,h); iterates 64-key tiles.
// K-tile (64 keys x 64d) and V-tile (64d x 64 keys, from VT) staged to LDS via
// global_load_lds (XOR-swizzled 16B groups), double-buffered, 1 barrier/iter.
// P (16q x 64key) round-trips per-wave LDS (stride 72) into A-operand layout.
// VALU diet: sigmoid = rcp(1+exp(s*(-scale))) -> no IEEE divide sequence.
__global__ __launch_bounds__(256) void attn_k(const u16* __restrict__ Q,
                                              const u16* __restrict__ Kb,
                                              const u16* __restrict__ VT,
                                              const float* __restrict__ temp_p,
                                              u16* __restrict__ Oa) {
    const int L = 2048, H = 16, D = 1024;
    __shared__ u16 Ks[2][64 * 64];
    __shared__ u16 Vs[2][64 * 64];
    __shared__ u16 plds[4][16 * 72];

    const int tid = threadIdx.x;
    const int w = tid >> 6, lane = tid & 63;
    const int l15 = lane & 15, quad = lane >> 4;
    const int bh = blockIdx.x >> 4;           // 16 blocks per (b,h)
    const int qb0 = (blockIdx.x & 15) << 7;   // 128 queries per block
    const int b = bh >> 4, h = bh & 15;
    const float nscale = -0.125f * temp_p[0]; // -(HD^-0.5 * temp)

    // Q fragments: 2 q-tiles x 2 dim-halves (k=32 each).
    short8 aq[2][2];
#pragma unroll
    for (int qt = 0; qt < 2; qt++) {
        size_t row = (size_t)(b * L + qb0 + w * 32 + qt * 16 + l15) * D + h * 64;
#pragma unroll
        for (int hf = 0; hf < 2; hf++)
            aq[qt][hf] = *(const short8*)(Q + row + hf * 32 + quad * 8);
    }

    const u16* Kbase = Kb + (size_t)(b * L) * D + h * 64;
    const u16* VTb   = VT + (size_t)bh * 64 * L;

    // Staging source pointers: slot i (0..511): row r=i>>3, slot-group gs=i&7,
    // source group gsrc = gs ^ (r&7). Thread covers i = tid and tid+256.
    const int i0 = tid, i1 = tid + 256;
    const int r0 = i0 >> 3, g0 = (i0 & 7) ^ (r0 & 7);
    const int r1 = i1 >> 3, g1 = (i1 & 7) ^ (r1 & 7);
    const u16* kS0 = Kbase + (size_t)r0 * D + g0 * 8;
    const u16* kS1 = Kbase + (size_t)r1 * D + g1 * 8;
    const u16* vS0 = VTb + (size_t)r0 * L + g0 * 8;
    const u16* vS1 = VTb + (size_t)r1 * L + g1 * 8;

    auto stage = [&](int buf, int mc) {
        // wave-uniform LDS bases; lanes fill base+lane*16B.
        async_copy16(kS0 + (size_t)mc * D, &Ks[buf][w << 9]);
        async_copy16(kS1 + (size_t)mc * D, &Ks[buf][2048 + (w << 9)]);
        async_copy16(vS0 + mc, &Vs[buf][w << 9]);
        async_copy16(vS1 + mc, &Vs[buf][2048 + (w << 9)]);
    };

    f32x4 acc[2][4];
#pragma unroll
    for (int i = 0; i < 2; i++)
#pragma unroll
        for (int j = 0; j < 4; j++) acc[i][j] = (f32x4){0.f, 0.f, 0.f, 0.f};
    float rs[2][4] = {{0.f,0.f,0.f,0.f},{0.f,0.f,0.f,0.f}};
    u16* P = plds[w];
    const int lsw = l15 & 7;   // read-side swizzle key

    stage(0, 0);
    __syncthreads();
    for (int it = 0; it < 32; it++) {
        int cur = it & 1;
        if (it < 31) stage(1 - cur, (it + 1) << 6);
        const u16* Kt = Ks[cur];
        const u16* Vt = Vs[cur];
#pragma unroll
        for (int qt = 0; qt < 2; qt++) {
#pragma unroll
            for (int ks = 0; ks < 4; ks++) {
                f32x4 s = (f32x4){0.f, 0.f, 0.f, 0.f};
#pragma unroll
                for (int hf = 0; hf < 2; hf++) {
                    int slot = ((ks * 16 + l15) * 8 + ((hf * 4 + quad) ^ lsw)) * 8;
                    short8 bk = *(const short8*)&Kt[slot];
                    s = __builtin_amdgcn_mfma_f32_16x16x32_bf16(aq[qt][hf], bk, s, 0, 0, 0);
                }
#pragma unroll
                for (int g = 0; g < 4; g++) {
                    float e = __expf(s[g] * nscale);        // mul + v_exp
                    float p = fast_rcp(1.f + e);            // v_rcp, no div seq
                    rs[qt][g] += p;
                    P[(quad * 4 + g) * 72 + ks * 16 + l15] = f2b(p);
                }
            }
#pragma unroll
            for (int kh = 0; kh < 2; kh++) {
                short8 ap = *(const short8*)&P[l15 * 72 + kh * 32 + quad * 8];
#pragma unroll
                for (int dt = 0; dt < 4; dt++) {
                    int slot = ((dt * 16 + l15) * 8 + ((kh * 4 + quad) ^ lsw)) * 8;
                    short8 bv = *(const short8*)&Vt[slot];
                    acc[qt][dt] = __builtin_amdgcn_mfma_f32_16x16x32_bf16(ap, bv, acc[qt][dt], 0, 0, 0);
                }
            }
        }
        __syncthreads();
    }

#pragma unroll
    for (int qt = 0; qt < 2; qt++)
#pragma unroll
        for (int g = 0; g < 4; g++) {
#pragma unroll
            for (int m = 1; m < 16; m <<= 1) rs[qt][g] += __shfl_xor(rs[qt][g], m, 64);
        }

#pragma unroll
    for (int qt = 0; qt < 2; qt++) {
        u16* orow = Oa + (size_t)(b * L + qb0 + w * 32 + qt * 16) * D + h * 64;
#pragma unroll
        for (int g = 0; g < 4; g++) {
            float rd = fast_rcp(fmaxf(rs[qt][g], 1.0f));
            int row = quad * 4 + g;
#pragma unroll
            for (int dt = 0; dt < 4; dt++)
                orow[(size_t)row * D + dt * 16 + l15] = f2b(acc[qt][dt][g] * rd);
        }
    }
}

// ---------------------------------------------------------------------------
// Glue kernels (all vectorized: 16B/lane loads/stores — G13).
// dst = concat([s0, s1], -1), rows of 1024. total = elems, 8/thread.
__global__ void concat2_k(u16* __restrict__ dst, const u16* __restrict__ s0,
                          const u16* __restrict__ s1, int total) {
    int i = (blockIdx.x * 256 + threadIdx.x) * 8;
    if (i >= total) return;
    int j = i & 1023;
    int t = i >> 10;
    int seg = t & 1;
    int n = t >> 1;
    const u16* s = seg ? s1 : s0;
    *(us8*)(dst + i) = *(const us8*)&s[(size_t)n * 1024 + j];
}

// cu_in = concat([connection(fp32), z1(bf16), dz(bf16)], -1), 8/thread.
__global__ void cucat_k(u16* __restrict__ dst, const float* __restrict__ conn,
                        const u16* __restrict__ z1, const u16* __restrict__ dz,
                        int total) {
    int i = (blockIdx.x * 256 + threadIdx.x) * 8;
    if (i >= total) return;
    int j = i & 1023;
    int t = i >> 10;
    int seg = t % 3;
    int n = t / 3;
    size_t src = (size_t)n * 1024 + j;
    if (seg == 0) {
        f32x4 a = *(const f32x4*)(conn + src);
        f32x4 b = *(const f32x4*)(conn + src + 4);
        us8 o;
#pragma unroll
        for (int k = 0; k < 4; k++) { o[k] = f2b(a[k]); o[k + 4] = f2b(b[k]); }
        *(us8*)(dst + i) = o;
    } else {
        const u16* s = (seg == 1) ? z1 : dz;
        *(us8*)(dst + i) = *(const us8*)&s[src];
    }
}

__global__ void dz_k(u16* __restrict__ d, const u16* __restrict__ a,
                     const u16* __restrict__ b, const float* __restrict__ dtp, int n) {
    int i = (blockIdx.x * 256 + threadIdx.x) * 8;
    if (i >= n) return;
    float dt = dtp[0];
    us8 va = *(const us8*)(a + i), vb = *(const us8*)(b + i);
    us8 o;
#pragma unroll
    for (int k = 0; k < 8; k++) o[k] = f2b(dt * (b2f(va[k]) + b2f(vb[k])));
    *(us8*)(d + i) = o;
}

// z1 = z(fp32) + dz(bf16) + ctx(bf16) -> bf16 internal
__global__ void z1_k(u16* __restrict__ d, const float* __restrict__ z,
                     const u16* __restrict__ dz, const u16* __restrict__ ctx, int n) {
    int i = (blockIdx.x * 256 + threadIdx.x) * 8;
    if (i >= n) return;
    f32x4 z0 = *(const f32x4*)(z + i), z4 = *(const f32x4*)(z + i + 4);
    us8 vd = *(const us8*)(dz + i), vc = *(const us8*)(ctx + i);
    us8 o;
#pragma unroll
    for (int k = 0; k < 4; k++) {
        o[k]     = f2b(z0[k] + b2f(vd[k])     + b2f(vc[k]));
        o[k + 4] = f2b(z4[k] + b2f(vd[k + 4]) + b2f(vc[k + 4]));
    }
    *(us8*)(d + i) = o;
}

// conn_new = connection(fp32) + delta(bf16) -> fp32 out
__global__ void connew_k(float* __restrict__ d, const float* __restrict__ conn,
                         const u16* __restrict__ delta, int n) {
    int i = (blockIdx.x * 256 + threadIdx.x) * 8;
    if (i >= n) return;
    f32x4 c0 = *(const f32x4*)(conn + i), c4 = *(const f32x4*)(conn + i + 4);
    us8 vd = *(const us8*)(delta + i);
    f32x4 o0, o4;
#pragma unroll
    for (int k = 0; k < 4; k++) {
        o0[k] = c0[k] + b2f(vd[k]);
        o4[k] = c4[k] + b2f(vd[k + 4]);
    }
    *(f32x4*)(d + i) = o0;
    *(f32x4*)(d + i + 4) = o4;
}

// z2 = z1(bf16) + mf(bf16) -> fp32 out
__global__ void z2_k(float* __restrict__ d, const u16* __restrict__ z1,
                     const u16* __restrict__ mf, int n) {
    int i = (blockIdx.x * 256 + threadIdx.x) * 8;
    if (i >= n) return;
    us8 va = *(const us8*)(z1 + i), vb = *(const us8*)(mf + i);
    f32x4 o0, o4;
#pragma unroll
    for (int k = 0; k < 4; k++) {
        o0[k] = b2f(va[k]) + b2f(vb[k]);
        o4[k] = b2f(va[k + 4]) + b2f(vb[k + 4]);
    }
    *(f32x4*)(d + i) = o0;
    *(f32x4*)(d + i + 4) = o4;
}

__global__ void copyf_k(float* __restrict__ d, const float* __restrict__ s, int n) {
    int i = (blockIdx.x * 256 + threadIdx.x) * 4;
    if (i >= n) return;
    *(f32x4*)(d + i) = *(const f32x4*)(s + i);
}

// ---------------------------------------------------------------------------
extern "C" void kernel_launch(void* const* d_in, const int* in_sizes, int n_in,
                              void* d_out, int out_size, void* d_ws, size_t ws_size,
                              hipStream_t stream) {
    const int B = 2, L = 2048, D = 1024, H = 16, N = B * L;
    const float* z      = (const float*)d_in[0];
    const float* conn   = (const float*)d_in[1];
    const float* w_z    = (const float*)d_in[2];
    const float* w_c    = (const float*)d_in[3];
    const float* w_mlp  = (const float*)d_in[4];
    const float* f_w1   = (const float*)d_in[5];
    const float* f_b1   = (const float*)d_in[6];
    const float* f_w2   = (const float*)d_in[7];
    const float* f_b2   = (const float*)d_in[8];
    const float* g_w1   = (const float*)d_in[9];
    const float* g_b1   = (const float*)d_in[10];
    const float* g_w2   = (const float*)d_in[11];
    const float* g_b2   = (const float*)d_in[12];
    const float* dt_p   = (const float*)d_in[13];
    const float* q_w    = (const float*)d_in[14];
    const float* k_w    = (const float*)d_in[15];
    const float* v_w    = (const float*)d_in[16];
    const float* o_w    = (const float*)d_in[17];
    const float* temp_p = (const float*)d_in[18];
    const float* cu_w1  = (const float*)d_in[19];
    const float* cu_b1  = (const float*)d_in[20];
    const float* cu_w2  = (const float*)d_in[21];
    const float* cu_b2  = (const float*)d_in[22];
    const float* m_w1   = (const float*)d_in[23];
    const float* m_b1   = (const float*)d_in[24];
    const float* m_w2   = (const float*)d_in[25];
    const float* m_b2   = (const float*)d_in[26];

    float* out = (float*)d_out;
    u16* ws  = (u16*)d_ws;
    const size_t U = (size_t)N * D;   // 4M elems

    // Activation slots (bf16), liveness-packed: peak slot index 8 (9 units).
    u16* zn    = ws + 0 * U;
    u16* cn    = ws + 1 * U;
    u16* h1    = ws + 2 * U;   // 2 units (2-3)
    u16* dzl   = ws + 4 * U;
    u16* gcat  = ws + 5 * U;   // 2 units (5-6)
    u16* gh    = ws + 7 * U;
    u16* corr  = ws + 5 * U;   // gcat dead
    u16* dz    = ws + 6 * U;
    u16* zc    = ws + 2 * U;   // 2 units (2-3), h1 dead
    u16* Qb    = ws + 4 * U;   // dzl dead
    u16* Kbuf  = ws + 5 * U;   // corr dead
    u16* VT    = ws + 7 * U;   // gh dead; VT[bh][64][L], 4M elems
    u16* attn  = ws + 8 * U;
    u16* ctx   = ws + 4 * U;   // Qb dead
    u16* z1    = ws + 5 * U;   // Kbuf dead
    u16* cu_in = ws + 0 * U;   // 3 units (0-2): zn,cn,zc dead
    u16* cu_h  = ws + 3 * U;   // 2 units (3-4): zc(3),ctx dead
    u16* delta = ws + 7 * U;   // VT dead
    u16* z1n   = ws + 0 * U;   // cu_in dead
    u16* mh    = ws + 1 * U;   // 4 units (1-4)
    u16* mf    = ws + 0 * U;   // z1n dead

    // bf16 weight copies after activation slots: 29M u16 elems.
    u16* wb = ws + 9 * U;
    u16* bf_w1  = wb + 0;                       // 2M
    u16* bf_w2  = wb + 2 * 1024 * 1024;         // 2M
    u16* bg_w1  = wb + 4 * 1024 * 1024;         // 2M
    u16* bg_w2  = wb + 6 * 1024 * 1024;         // 1M
    u16* bq_w   = wb + 7 * 1024 * 1024;         // 2M
    u16* bk_w   = wb + 9 * 1024 * 1024;         // 2M
    u16* bv_w   = wb + 11 * 1024 * 1024;        // 1M
    u16* bo_w   = wb + 12 * 1024 * 1024;        // 1M
    u16* bcu_w1 = wb + 13 * 1024 * 1024;        // 6M
    u16* bcu_w2 = wb + 19 * 1024 * 1024;        // 2M
    u16* bm_w1  = wb + 21 * 1024 * 1024;        // 4M
    u16* bm_w2  = wb + 25 * 1024 * 1024;        // 4M

    auto cvt = [&](const float* s, u16* d, int n) {
        cvt_k<<<n / 1024, 256, 0, stream>>>(s, d, n);
    };
    cvt(f_w1, bf_w1, 2 * D * D);   cvt(f_w2, bf_w2, 2 * D * D);
    cvt(g_w1, bg_w1, 2 * D * D);   cvt(g_w2, bg_w2, D * D);
    cvt(q_w, bq_w, 2 * D * D);     cvt(k_w, bk_w, 2 * D * D);
    cvt(v_w, bv_w, D * D);         cvt(o_w, bo_w, D * D);
    cvt(cu_w1, bcu_w1, 6 * D * D); cvt(cu_w2, bcu_w2, 2 * D * D);
    cvt(m_w1, bm_w1, 4 * D * D);   cvt(m_w2, bm_w2, 4 * D * D);

    const int EW8 = (N * D / 8 + 255) / 256;
    auto gemm = [&](const u16* A, const u16* W, const float* bias, u16* C,
                    int K, int O, int act, int mode = 0) {
        if (O == 1024) {
            // 1 block/CU at BN=128 (grid 256) -> BN=64 doubles occupancy.
            dim3 grid(O / 64, N / 128);
            gemm_t<64><<<grid, 256, 0, stream>>>(A, W, bias, C, K, O, act, mode);
        } else {
            dim3 grid(O / 128, N / 128);
            gemm_t<128><<<grid, 256, 0, stream>>>(A, W, bias, C, K, O, act, mode);
        }
    };

    rmsf_k<<<N, 256, 0, stream>>>(z, w_z, zn, D);
    rmsf_k<<<N, 256, 0, stream>>>(conn, w_c, cn, D);

    gemm(zn, bf_w1, f_b1, h1, D, 2 * D, 1);                  // silu
    gemm(h1, bf_w2, f_b2, dzl, 2 * D, D, 0);
    concat2_k<<<(N * 2 * D / 8 + 255) / 256, 256, 0, stream>>>(gcat, cn, dzl, N * 2 * D);
    gemm(gcat, bg_w1, g_b1, gh, 2 * D, D, 2);                // tanh
    gemm(gh, bg_w2, g_b2, corr, D, D, 0);
    dz_k<<<EW8, 256, 0, stream>>>(dz, dzl, corr, dt_p, N * D);

    concat2_k<<<(N * 2 * D / 8 + 255) / 256, 256, 0, stream>>>(zc, zn, cn, N * 2 * D);
    gemm(zc, bq_w, nullptr, Qb, 2 * D, D, 0);
    gemm(zc, bk_w, nullptr, Kbuf, 2 * D, D, 0);
    gemm(zn, bv_w, nullptr, VT, D, D, 0, 1);                 // V, transposed per head
    attn_k<<<B * H * L / 128, 256, 0, stream>>>(Qb, Kbuf, VT, temp_p, attn);
    gemm(attn, bo_w, nullptr, ctx, D, D, 0);

    z1_k<<<EW8, 256, 0, stream>>>(z1, z, dz, ctx, N * D);

    cucat_k<<<(N * 3 * D / 8 + 255) / 256, 256, 0, stream>>>(cu_in, conn, z1, dz, N * 3 * D);
    gemm(cu_in, bcu_w1, cu_b1, cu_h, 3 * D, 2 * D, 1);       // silu
    gemm(cu_h, bcu_w2, cu_b2, delta, 2 * D, D, 0);
    connew_k<<<EW8, 256, 0, stream>>>(out + U, conn, delta, N * D);   // conn_new
    copyf_k<<<(N * D + 1023) / 1024, 256, 0, stream>>>(out + 2 * U, z, N * D); // z_before

    rmsb_k<<<N, 256, 0, stream>>>(z1, w_mlp, z1n, D);
    gemm(z1n, bm_w1, m_b1, mh, D, 4 * D, 1);                 // silu
    gemm(mh, bm_w2, m_b2, mf, 4 * D, D, 0);
    z2_k<<<EW8, 256, 0, stream>>>(out, z1, mf, N * D);                // z2
}

// Round 2
// 749.875 us; speedup vs baseline: 1.3506x; 1.1739x over previous
//
#include <hip/hip_runtime.h>

// CovariantEvolutionBlock on MI355X (gfx950).
// I/O is float32 (bf16-grid values); internal compute bf16 MFMA + fp32 accum.
// B=2, L=2048, D=1024, H=16, HD=64, N=B*L=4096 tokens.

typedef unsigned short u16;
typedef __attribute__((ext_vector_type(8))) short short8;
typedef __attribute__((ext_vector_type(8))) unsigned short us8;
typedef __attribute__((ext_vector_type(4))) float f32x4;
typedef __attribute__((ext_vector_type(4))) unsigned short us4;
typedef __attribute__((ext_vector_type(2))) unsigned int u32x2;

__device__ __forceinline__ float b2f(u16 u) {
    union { unsigned u; float f; } c; c.u = ((unsigned)u) << 16; return c.f;
}
__device__ __forceinline__ u16 f2b(float f) {
    union { float f; unsigned u; } c; c.f = f;
    unsigned x = c.u;
    unsigned r = (x + 0x7fffu + ((x >> 16) & 1u)) >> 16;   // RNE
    return (u16)r;
}
__device__ __forceinline__ float fast_rcp(float x) {
    return __builtin_amdgcn_rcpf(x);     // v_rcp_f32, ~1 ulp, fine pre-bf16
}
// HW packed f32->bf16 (RNE), 1 instruction for 2 values.
__device__ __forceinline__ unsigned cvt_pk_bf16(float a, float b) {
    unsigned r;
    asm("v_cvt_pk_bf16_f32 %0, %1, %2" : "=v"(r) : "v"(a), "v"(b));
    return r;
}

__device__ __forceinline__ void async_copy16(const u16* g, u16* l) {
    __builtin_amdgcn_global_load_lds(
        (const __attribute__((address_space(1))) unsigned int*)(g),
        (__attribute__((address_space(3))) unsigned int*)(l), 16, 0, 0);
}

// ---------------------------------------------------------------------------
// fp32 -> bf16 conversion, 4 elems/thread. n must be a multiple of 1024.
__global__ __launch_bounds__(256) void cvt_k(const float* __restrict__ s,
                                             u16* __restrict__ d, int n) {
    int i = (blockIdx.x * 256 + threadIdx.x) * 4;
    if (i >= n) return;
    f32x4 v = *(const f32x4*)(s + i);
    us4 o;
#pragma unroll
    for (int k = 0; k < 4; k++) o[k] = f2b(v[k]);
    *(us4*)(d + i) = o;
}

// ---------------------------------------------------------------------------
// RMSNorm from fp32 input: one block per token, D=1024, 256 threads x 4 contig.
// Optional cp: raw fp32 copy-out (folds the z_before copy into the z pass).
__global__ __launch_bounds__(256) void rmsf_k(const float* __restrict__ x,
                                              const float* __restrict__ w,
                                              u16* __restrict__ y,
                                              float* __restrict__ cp, int D) {
    int n = blockIdx.x;
    const float* xr = x + (size_t)n * D;
    int i0 = threadIdx.x << 2;
    f32x4 v = *(const f32x4*)(xr + i0);
    if (cp) *(f32x4*)(cp + (size_t)n * D + i0) = v;
    float s = v[0] * v[0] + v[1] * v[1] + v[2] * v[2] + v[3] * v[3];
#pragma unroll
    for (int m = 32; m >= 1; m >>= 1) s += __shfl_xor(s, m, 64);
    __shared__ float red[4];
    if ((threadIdx.x & 63) == 0) red[threadIdx.x >> 6] = s;
    __syncthreads();
    float tot = red[0] + red[1] + red[2] + red[3];
    float scale = rsqrtf(tot / (float)D + 1e-6f);
    f32x4 wv = *(const f32x4*)(w + i0);
    us4 o;
#pragma unroll
    for (int k = 0; k < 4; k++) o[k] = f2b(v[k] * scale * wv[k]);
    *(us4*)(y + (size_t)n * D + i0) = o;
}

// RMSNorm from bf16 (internal) input.
__global__ __launch_bounds__(256) void rmsb_k(const u16* __restrict__ x,
                                              const float* __restrict__ w,
                                              u16* __restrict__ y, int D) {
    int n = blockIdx.x;
    const u16* xr = x + (size_t)n * D;
    int i0 = threadIdx.x << 2;
    us4 xv = *(const us4*)(xr + i0);
    float v[4]; float s = 0.f;
#pragma unroll
    for (int k = 0; k < 4; k++) { v[k] = b2f(xv[k]); s += v[k] * v[k]; }
#pragma unroll
    for (int m = 32; m >= 1; m >>= 1) s += __shfl_xor(s, m, 64);
    __shared__ float red[4];
    if ((threadIdx.x & 63) == 0) red[threadIdx.x >> 6] = s;
    __syncthreads();
    float tot = red[0] + red[1] + red[2] + red[3];
    float scale = rsqrtf(tot / (float)D + 1e-6f);
    f32x4 wv = *(const f32x4*)(w + i0);
    us4 o;
#pragma unroll
    for (int k = 0; k < 4; k++) o[k] = f2b(v[k] * scale * wv[k]);
    *(us4*)(y + (size_t)n * D + i0) = o;
}

// ---------------------------------------------------------------------------
// Tiled NT GEMM: C[n,o] = act(sum_k A[n,k]*W[o,k] + bias[o]).
// BM=128 x BN(128|64), BK=64, 4 waves (2x2), global_load_lds staging with
// XOR-swizzled (8-group) source addressing, LDS double-buffer, ONE barrier per
// 64-wide K-step (32 MFMA per drain — halves the vmcnt(0)+barrier stalls).
// A-operand is a virtual concat of NSEG segments, each with native row stride
// 1024 (NSEG=1: single contiguous matrix, stride K) — no concat buffers.
// act: 0=none 1=silu 2=tanh. grid = (O/BN, M/128).
// mode: 0 = row-major C; 1 = per-head transpose for attention V:
//       C is VT[((b*16+h)*64 + d)*2048 + tok].
template <int BN, int NSEG>
__global__ __launch_bounds__(256) void gemm_t(const u16* __restrict__ A0,
                                              const u16* __restrict__ A1,
                                              const u16* __restrict__ A2,
                                              const u16* __restrict__ W,
                                              const float* __restrict__ bias,
                                              u16* __restrict__ C,
                                              int K, int O, int act, int mode) {
    constexpr int NJ = BN / 32;          // n-subtiles per wave: 4 or 2
    constexpr int WN = BN / 2;           // wave n-extent: 64 or 32
    __shared__ u16 Asm[2][128 * 64];
    __shared__ u16 Bsm[2][BN * 64];

    const int tid = threadIdx.x;
    const int wid = tid >> 6, lane = tid & 63;
    const int l15 = lane & 15, quad = lane >> 4;
    const int lsw = l15 & 7;
    const int row0 = blockIdx.y * 128, col0 = blockIdx.x * BN;
    const int wm = (wid >> 1) << 6, wn = (wid & 1) * WN;

    // Staging: slot s in [0,1024): row r=s>>3, group g=s&7; LDS[r][g] holds
    // source group g^(r&7) (linear dest, pre-swizzled per-lane source).
    const int rb = tid >> 3;                       // 0..31
    const int gg = ((tid & 7) ^ (rb & 7)) << 3;    // source col offset, elems
    const int sA = (NSEG == 1) ? K : 1024;         // A row stride
    const size_t aoff = (size_t)(row0 + rb) * sA + gg;
    const size_t boff = (size_t)(col0 + rb) * K + gg;
    const int ldsb = wid << 9;                     // wave base within async blk

    f32x4 acc[4][NJ];
#pragma unroll
    for (int i = 0; i < 4; i++)
#pragma unroll
        for (int j = 0; j < NJ; j++) acc[i][j] = (f32x4){0.f, 0.f, 0.f, 0.f};

    auto stage = [&](int buf, int kof) {
        const u16* Ab; int kcol;
        if constexpr (NSEG == 1) { Ab = A0; kcol = kof; }
        else {
            int seg = kof >> 10;                   // BK=64 never crosses a seg
            Ab = (seg == 0) ? A0 : ((NSEG == 3 && seg == 2) ? A2 : A1);
            kcol = kof & 1023;
        }
        const u16* as = Ab + aoff + kcol;
        const u16* bs = W + boff + kof;
#pragma unroll
        for (int i = 0; i < 4; i++)
            async_copy16(as + (size_t)(32 * i) * sA, &Asm[buf][(i << 11) + ldsb]);
#pragma unroll
        for (int i = 0; i < BN / 32; i++)
            async_copy16(bs + (size_t)(32 * i) * K, &Bsm[buf][(i << 11) + ldsb]);
    };

    const int nk = K >> 6;
    stage(0, 0);
    __syncthreads();
    for (int kk = 0; kk < nk; kk++) {
        int cur = kk & 1;
        if (kk + 1 < nk) stage(1 - cur, (kk + 1) << 6);
        const u16* Ab = Asm[cur];
        const u16* Bb = Bsm[cur];
#pragma unroll
        for (int h = 0; h < 2; h++) {
            const int gq = (((h << 2) + quad) ^ lsw) << 3;
            short8 af[4], bf[NJ];
#pragma unroll
            for (int i = 0; i < 4; i++)
                af[i] = *(const short8*)&Ab[(wm + i * 16 + l15) * 64 + gq];
#pragma unroll
            for (int j = 0; j < NJ; j++)
                bf[j] = *(const short8*)&Bb[(wn + j * 16 + l15) * 64 + gq];
#pragma unroll
            for (int i = 0; i < 4; i++)
#pragma unroll
                for (int j = 0; j < NJ; j++)
                    acc[i][j] = __builtin_amdgcn_mfma_f32_16x16x32_bf16(af[i], bf[j], acc[i][j], 0, 0, 0);
        }
        __syncthreads();
    }

    if (mode == 0) {
#pragma unroll
        for (int j = 0; j < NJ; j++) {
            int col = col0 + wn + j * 16 + l15;
            float bb = bias ? bias[col] : 0.f;
#pragma unroll
            for (int i = 0; i < 4; i++) {
                int rowb = row0 + wm + i * 16 + (quad << 2);
#pragma unroll
                for (int g = 0; g < 4; g++) {
                    float v = acc[i][j][g] + bb;
                    if (act == 1) {                      // silu
                        v = v * fast_rcp(1.f + __expf(-v));
                    } else if (act == 2) {               // tanh = 1 - 2/(e^2x+1)
                        float t = __expf(v * 2.f);
                        v = 1.f - 2.f * fast_rcp(1.f + t);
                    }
                    C[(size_t)(rowb + g) * O + col] = f2b(v);
                }
            }
        }
    } else {
        // V-transpose epilogue: 4 consecutive toks -> one 8B store VT[bh][d][tok].
#pragma unroll
        for (int j = 0; j < NJ; j++) {
            int col = col0 + wn + j * 16 + l15;     // h*64 + d
            int h = col >> 6, d = col & 63;
#pragma unroll
            for (int i = 0; i < 4; i++) {
                int rowb = row0 + wm + i * 16 + (quad << 2);
                int bb_ = rowb >> 11;               // batch
                int tok = rowb & 2047;
                us4 pk;
#pragma unroll
                for (int g = 0; g < 4; g++) pk[g] = f2b(acc[i][j][g]);
                *(us4*)&C[(size_t)(((bb_ << 4) + h) * 64 + d) * 2048 + tok] = pk;
            }
        }
    }
}

// ---------------------------------------------------------------------------
// Sigmoid attention v4: block-cooperative flash-style, swapped QK^T.
// Block = 256 thr = 4 waves = 128 queries of one (b,h); iterates 64-key tiles.
// Q,K come from the fused QK buffer (row stride 2048: Q cols 0-1023, K 1024+).
// QK^T computed as mfma(K,Q): output row=key, col=q -> each lane holds 4
// CONSECUTIVE keys of one q-row. Sigmoid then packs via 2x v_cvt_pk_bf16_f32
// and ONE ds_write_b64 (was 4 scalar b16 writes + 4x5-op manual f2b).
// rs is one register/lane (q = l15), reduced across quad (strides 16,32).
__global__ __launch_bounds__(256) void attn_k(const u16* __restrict__ QK,
                                              const u16* __restrict__ VT,
                                              const float* __restrict__ temp_p,
                                              u16* __restrict__ Oa) {
    const int L = 2048, D = 1024, SQ = 2048;
    __shared__ u16 Ks[2][64 * 64];
    __shared__ u16 Vs[2][64 * 64];
    __shared__ u16 plds[4][16 * 72];

    const int tid = threadIdx.x;
    const int w = tid >> 6, lane = tid & 63;
    const int l15 = lane & 15, quad = lane >> 4;
    const int bh = blockIdx.x >> 4;           // 16 blocks per (b,h)
    const int qb0 = (blockIdx.x & 15) << 7;   // 128 queries per block
    const int b = bh >> 4, h = bh & 15;
    const float nsc2 = -0.125f * temp_p[0] * 1.44269504f;  // fold log2(e)

    // Q fragments: 2 q-tiles x 2 dim-halves (k=32 each).
    short8 aq[2][2];
#pragma unroll
    for (int qt = 0; qt < 2; qt++) {
        size_t row = (size_t)(b * L + qb0 + w * 32 + qt * 16 + l15) * SQ + h * 64;
#pragma unroll
        for (int hf = 0; hf < 2; hf++)
            aq[qt][hf] = *(const short8*)(QK + row + hf * 32 + quad * 8);
    }

    const u16* Kbase = QK + 1024 + (size_t)(b * L) * SQ + h * 64;
    const u16* VTb   = VT + (size_t)bh * 64 * L;

    // Staging: slot i (0..511): row r=i>>3, group gs=i&7, src group gs^(r&7).
    const int i0 = tid, i1 = tid + 256;
    const int r0 = i0 >> 3, g0 = (i0 & 7) ^ (r0 & 7);
    const int r1 = i1 >> 3, g1 = (i1 & 7) ^ (r1 & 7);
    const u16* kS0 = Kbase + (size_t)r0 * SQ + g0 * 8;
    const u16* kS1 = Kbase + (size_t)r1 * SQ + g1 * 8;
    const u16* vS0 = VTb + (size_t)r0 * L + g0 * 8;
    const u16* vS1 = VTb + (size_t)r1 * L + g1 * 8;

    auto stage = [&](int buf, int mc) {
        async_copy16(kS0 + (size_t)mc * SQ, &Ks[buf][w << 9]);
        async_copy16(kS1 + (size_t)mc * SQ, &Ks[buf][2048 + (w << 9)]);
        async_copy16(vS0 + mc, &Vs[buf][w << 9]);
        async_copy16(vS1 + mc, &Vs[buf][2048 + (w << 9)]);
    };

    f32x4 acc[2][4];
#pragma unroll
    for (int i = 0; i < 2; i++)
#pragma unroll
        for (int j = 0; j < 4; j++) acc[i][j] = (f32x4){0.f, 0.f, 0.f, 0.f};
    float rs[2] = {0.f, 0.f};
    u16* P = plds[w];
    const int lsw = l15 & 7;   // read-side swizzle key

    stage(0, 0);
    __syncthreads();
    for (int it = 0; it < 32; it++) {
        int cur = it & 1;
        if (it < 31) stage(1 - cur, (it + 1) << 6);
        const u16* Kt = Ks[cur];
        const u16* Vt = Vs[cur];
#pragma unroll
        for (int qt = 0; qt < 2; qt++) {
#pragma unroll
            for (int ks = 0; ks < 4; ks++) {
                f32x4 s = (f32x4){0.f, 0.f, 0.f, 0.f};
#pragma unroll
                for (int hf = 0; hf < 2; hf++) {
                    int slot = ((ks * 16 + l15) * 8 + ((hf * 4 + quad) ^ lsw)) * 8;
                    short8 bk = *(const short8*)&Kt[slot];
                    // swapped: A=K (row=key), B=Q (col=q)
                    s = __builtin_amdgcn_mfma_f32_16x16x32_bf16(bk, aq[qt][hf], s, 0, 0, 0);
                }
                float p0 = fast_rcp(1.f + __builtin_amdgcn_exp2f(s[0] * nsc2));
                float p1 = fast_rcp(1.f + __builtin_amdgcn_exp2f(s[1] * nsc2));
                float p2 = fast_rcp(1.f + __builtin_amdgcn_exp2f(s[2] * nsc2));
                float p3 = fast_rcp(1.f + __builtin_amdgcn_exp2f(s[3] * nsc2));
                rs[qt] += (p0 + p1) + (p2 + p3);
                u32x2 pk2;
                pk2[0] = cvt_pk_bf16(p0, p1);
                pk2[1] = cvt_pk_bf16(p2, p3);
                // P[q = l15][key = ks*16 + quad*4 .. +3], 8B aligned store
                *(u32x2*)&P[l15 * 72 + ks * 16 + (quad << 2)] = pk2;
            }
#pragma unroll
            for (int kh = 0; kh < 2; kh++) {
                short8 ap = *(const short8*)&P[l15 * 72 + kh * 32 + quad * 8];
#pragma unroll
                for (int dt = 0; dt < 4; dt++) {
                    int slot = ((dt * 16 + l15) * 8 + ((kh * 4 + quad) ^ lsw)) * 8;
                    short8 bv = *(const short8*)&Vt[slot];
                    acc[qt][dt] = __builtin_amdgcn_mfma_f32_16x16x32_bf16(ap, bv, acc[qt][dt], 0, 0, 0);
                }
            }
        }
        __syncthreads();
    }

    // rs: per-lane partial over its quad's keys; reduce across quad dimension.
#pragma unroll
    for (int qt = 0; qt < 2; qt++) {
        rs[qt] += __shfl_xor(rs[qt], 16, 64);
        rs[qt] += __shfl_xor(rs[qt], 32, 64);
    }

#pragma unroll
    for (int qt = 0; qt < 2; qt++) {
        u16* orow = Oa + (size_t)(b * L + qb0 + w * 32 + qt * 16) * D + h * 64;
#pragma unroll
        for (int g = 0; g < 4; g++) {
            int row = quad * 4 + g;
            float denom = __shfl(rs[qt], row, 64);   // lane 'row' holds q=row
            float rd = fast_rcp(fmaxf(denom, 1.0f));
#pragma unroll
            for (int dt = 0; dt < 4; dt++)
                orow[(size_t)row * D + dt * 16 + l15] = f2b(acc[qt][dt][g] * rd);
        }
    }
}

// ---------------------------------------------------------------------------
// Glue kernels (all vectorized: 16B/lane loads/stores).
__global__ void dz_k(u16* __restrict__ d, const u16* __restrict__ a,
                     const u16* __restrict__ b, const float* __restrict__ dtp, int n) {
    int i = (blockIdx.x * 256 + threadIdx.x) * 8;
    if (i >= n) return;
    float dt = dtp[0];
    us8 va = *(const us8*)(a + i), vb = *(const us8*)(b + i);
    us8 o;
#pragma unroll
    for (int k = 0; k < 8; k++) o[k] = f2b(dt * (b2f(va[k]) + b2f(vb[k])));
    *(us8*)(d + i) = o;
}

// z1 = z(fp32) + dz(bf16) + ctx(bf16) -> bf16 internal
__global__ void z1_k(u16* __restrict__ d, const float* __restrict__ z,
                     const u16* __restrict__ dz, const u16* __restrict__ ctx, int n) {
    int i = (blockIdx.x * 256 + threadIdx.x) * 8;
    if (i >= n) return;
    f32x4 z0 = *(const f32x4*)(z + i), z4 = *(const f32x4*)(z + i + 4);
    us8 vd = *(const us8*)(dz + i), vc = *(const us8*)(ctx + i);
    us8 o;
#pragma unroll
    for (int k = 0; k < 4; k++) {
        o[k]     = f2b(z0[k] + b2f(vd[k])     + b2f(vc[k]));
        o[k + 4] = f2b(z4[k] + b2f(vd[k + 4]) + b2f(vc[k + 4]));
    }
    *(us8*)(d + i) = o;
}

// conn_new = connection(fp32) + delta(bf16) -> fp32 out
__global__ void connew_k(float* __restrict__ d, const float* __restrict__ conn,
                         const u16* __restrict__ delta, int n) {
    int i = (blockIdx.x * 256 + threadIdx.x) * 8;
    if (i >= n) return;
    f32x4 c0 = *(const f32x4*)(conn + i), c4 = *(const f32x4*)(conn + i + 4);
    us8 vd = *(const us8*)(delta + i);
    f32x4 o0, o4;
#pragma unroll
    for (int k = 0; k < 4; k++) {
        o0[k] = c0[k] + b2f(vd[k]);
        o4[k] = c4[k] + b2f(vd[k + 4]);
    }
    *(f32x4*)(d + i) = o0;
    *(f32x4*)(d + i + 4) = o4;
}

// z2 = z1(bf16) + mf(bf16) -> fp32 out
__global__ void z2_k(float* __restrict__ d, const u16* __restrict__ z1,
                     const u16* __restrict__ mf, int n) {
    int i = (blockIdx.x * 256 + threadIdx.x) * 8;
    if (i >= n) return;
    us8 va = *(const us8*)(z1 + i), vb = *(const us8*)(mf + i);
    f32x4 o0, o4;
#pragma unroll
    for (int k = 0; k < 4; k++) {
        o0[k] = b2f(va[k]) + b2f(vb[k]);
        o4[k] = b2f(va[k + 4]) + b2f(vb[k + 4]);
    }
    *(f32x4*)(d + i) = o0;
    *(f32x4*)(d + i + 4) = o4;
}

// ---------------------------------------------------------------------------
extern "C" void kernel_launch(void* const* d_in, const int* in_sizes, int n_in,
                              void* d_out, int out_size, void* d_ws, size_t ws_size,
                              hipStream_t stream) {
    const int B = 2, L = 2048, D = 1024, H = 16, N = B * L;
    const float* z      = (const float*)d_in[0];
    const float* conn   = (const float*)d_in[1];
    const float* w_z    = (const float*)d_in[2];
    const float* w_c    = (const float*)d_in[3];
    const float* w_mlp  = (const float*)d_in[4];
    const float* f_w1   = (const float*)d_in[5];
    const float* f_b1   = (const float*)d_in[6];
    const float* f_w2   = (const float*)d_in[7];
    const float* f_b2   = (const float*)d_in[8];
    const float* g_w1   = (const float*)d_in[9];
    const float* g_b1   = (const float*)d_in[10];
    const float* g_w2   = (const float*)d_in[11];
    const float* g_b2   = (const float*)d_in[12];
    const float* dt_p   = (const float*)d_in[13];
    const float* q_w    = (const float*)d_in[14];
    const float* k_w    = (const float*)d_in[15];
    const float* v_w    = (const float*)d_in[16];
    const float* o_w    = (const float*)d_in[17];
    const float* temp_p = (const float*)d_in[18];
    const float* cu_w1  = (const float*)d_in[19];
    const float* cu_b1  = (const float*)d_in[20];
    const float* cu_w2  = (const float*)d_in[21];
    const float* cu_b2  = (const float*)d_in[22];
    const float* m_w1   = (const float*)d_in[23];
    const float* m_b1   = (const float*)d_in[24];
    const float* m_w2   = (const float*)d_in[25];
    const float* m_b2   = (const float*)d_in[26];

    float* out = (float*)d_out;
    u16* ws  = (u16*)d_ws;
    const size_t U = (size_t)N * D;   // 4M elems

    // Activation slots (bf16), liveness-packed, peak 9 units:
    // slot0: zn -> z1n
    // slot1: cn -> attnb -> delta -> mh[0]
    // slot2: h1[0] -> QK[0] -> cu_h[0] -> mh[1]
    // slot3: h1[1] -> QK[1] -> cu_h[1] -> mh[2]
    // slot4: dzl -> VT -> ctx -> mh[3]
    // slot5: gh -> z1
    // slot6: corr -> mf
    // slot7: dz
    // slot8: connb
    u16* zn    = ws + 0 * U;
    u16* cn    = ws + 1 * U;
    u16* h1    = ws + 2 * U;   // 2 units
    u16* dzl   = ws + 4 * U;
    u16* gh    = ws + 5 * U;
    u16* corr  = ws + 6 * U;
    u16* dz    = ws + 7 * U;
    u16* connb = ws + 8 * U;
    u16* QK    = ws + 2 * U;   // 2 units (h1 dead): [N][2048], Q|K
    u16* VT    = ws + 4 * U;   // dzl dead; VT[bh][64][L]
    u16* attnb = ws + 1 * U;   // cn dead after QK gemm
    u16* ctx   = ws + 4 * U;   // VT dead after attn
    u16* z1    = ws + 5 * U;   // gh dead
    u16* cu_h  = ws + 2 * U;   // 2 units, QK dead after attn
    u16* delta = ws + 1 * U;   // attnb dead after o gemm
    u16* z1n   = ws + 0 * U;   // zn dead
    u16* mh    = ws + 1 * U;   // 4 units (1-4): delta, cu_h, ctx dead
    u16* mf    = ws + 6 * U;   // corr dead

    // bf16 weight copies after activation slots: 29M u16 elems.
    u16* wb = ws + 9 * U;
    u16* bf_w1  = wb + 0;                       // 2M
    u16* bf_w2  = wb + 2 * 1024 * 1024;         // 2M
    u16* bg_w1  = wb + 4 * 1024 * 1024;         // 2M
    u16* bg_w2  = wb + 6 * 1024 * 1024;         // 1M
    u16* bqk_w  = wb + 7 * 1024 * 1024;         // 4M: q_w rows then k_w rows
    u16* bv_w   = wb + 11 * 1024 * 1024;        // 1M
    u16* bo_w   = wb + 12 * 1024 * 1024;        // 1M
    u16* bcu_w1 = wb + 13 * 1024 * 1024;        // 6M
    u16* bcu_w2 = wb + 19 * 1024 * 1024;        // 2M
    u16* bm_w1  = wb + 21 * 1024 * 1024;        // 4M
    u16* bm_w2  = wb + 25 * 1024 * 1024;        // 4M

    auto cvt = [&](const float* s, u16* d, int n) {
        cvt_k<<<n / 1024, 256, 0, stream>>>(s, d, n);
    };
    cvt(f_w1, bf_w1, 2 * D * D);   cvt(f_w2, bf_w2, 2 * D * D);
    cvt(g_w1, bg_w1, 2 * D * D);   cvt(g_w2, bg_w2, D * D);
    cvt(q_w, bqk_w, 2 * D * D);    cvt(k_w, bqk_w + 2 * D * D, 2 * D * D);
    cvt(v_w, bv_w, D * D);         cvt(o_w, bo_w, D * D);
    cvt(cu_w1, bcu_w1, 6 * D * D); cvt(cu_w2, bcu_w2, 2 * D * D);
    cvt(m_w1, bm_w1, 4 * D * D);   cvt(m_w2, bm_w2, 4 * D * D);
    cvt(conn, connb, N * D);       // bf16 connection for cu_w1 segment read

    const int EW8 = (N * D / 8 + 255) / 256;
    // Single-segment GEMM dispatch.
    auto gemm = [&](const u16* A, const u16* W, const float* bias, u16* C,
                    int K, int O, int act, int mode = 0) {
        if (O == 1024) {
            dim3 grid(16, 32);
            gemm_t<64, 1><<<grid, 256, 0, stream>>>(A, nullptr, nullptr, W, bias, C, K, O, act, mode);
        } else {
            dim3 grid(O / 128, 32);
            gemm_t<128, 1><<<grid, 256, 0, stream>>>(A, nullptr, nullptr, W, bias, C, K, O, act, mode);
        }
    };

    rmsf_k<<<N, 256, 0, stream>>>(z, w_z, zn, out + 2 * U, D);       // + z_before copy
    rmsf_k<<<N, 256, 0, stream>>>(conn, w_c, cn, nullptr, D);

    gemm(zn, bf_w1, f_b1, h1, D, 2 * D, 1);                          // silu
    gemm(h1, bf_w2, f_b2, dzl, 2 * D, D, 0);
    gemm_t<64, 2><<<dim3(16, 32), 256, 0, stream>>>(                 // [cn|dzl] tanh
        cn, dzl, nullptr, bg_w1, g_b1, gh, 2 * D, D, 2, 0);
    gemm(gh, bg_w2, g_b2, corr, D, D, 0);
    dz_k<<<EW8, 256, 0, stream>>>(dz, dzl, corr, dt_p, N * D);

    gemm_t<128, 2><<<dim3(16, 32), 256, 0, stream>>>(                // fused Q,K
        zn, cn, nullptr, bqk_w, nullptr, QK, 2 * D, 2 * D, 0, 0);
    gemm(zn, bv_w, nullptr, VT, D, D, 0, 1);                         // V, transposed
    attn_k<<<B * H * L / 128, 256, 0, stream>>>(QK, VT, temp_p, attnb);
    gemm(attnb, bo_w, nullptr, ctx, D, D, 0);

    z1_k<<<EW8, 256, 0, stream>>>(z1, z, dz, ctx, N * D);

    gemm_t<128, 3><<<dim3(16, 32), 256, 0, stream>>>(                // [connb|z1|dz] silu
        connb, z1, dz, bcu_w1, cu_b1, cu_h, 3 * D, 2 * D, 1, 0);
    gemm(cu_h, bcu_w2, cu_b2, delta, 2 * D, D, 0);
    connew_k<<<EW8, 256, 0, stream>>>(out + U, conn, delta, N * D);  // conn_new

    rmsb_k<<<N, 256, 0, stream>>>(z1, w_mlp, z1n, D);
    gemm(z1n, bm_w1, m_b1, mh, D, 4 * D, 1);                         // silu
    gemm(mh, bm_w2, m_b2, mf, 4 * D, D, 0);
    z2_k<<<EW8, 256, 0, stream>>>(out, z1, mf, N * D);               // z2
}